// Round 2
// baseline (1838.299 us; speedup 1.0000x reference)
//
#include <hip/hip_runtime.h>

// Workspace requirement: ~58.3 MB (z: N*256 f32 + ebuf: E*2 f32 + small per-node arrays).

// ---------- helpers: order-preserving float<->uint map for atomicMax ----------
__device__ __forceinline__ unsigned f2ord(float f) {
  unsigned u = __float_as_uint(f);
  return (u & 0x80000000u) ? ~u : (u | 0x80000000u);
}
__device__ __forceinline__ float ord2f(unsigned s) {
  unsigned u = (s & 0x80000000u) ? (s & 0x7fffffffu) : ~s;
  return __uint_as_float(u);
}

// ---------- zero fill (graph-capture-safe) ----------
__global__ __launch_bounds__(256) void zero_f4(float4* __restrict__ p, int n4) {
  int i = blockIdx.x * 256 + threadIdx.x;
  if (i < n4) p[i] = make_float4(0.f, 0.f, 0.f, 0.f);
}

// ---------- C[M,N] = A[M,K] @ B[K,N]; N,K multiples of 64/16; row-guard on M ----------
__global__ __launch_bounds__(256) void gemm_tile(const float* __restrict__ A,
                                                 const float* __restrict__ B,
                                                 float* __restrict__ C,
                                                 int M, int N, int K) {
  __shared__ float As[16][64];
  __shared__ float Bs[16][64];
  const int tid = threadIdx.x;
  const int row0 = blockIdx.x * 64;
  const int col0 = blockIdx.y * 64;
  const int ty = tid >> 4, tx = tid & 15;        // compute map: rows ty*4.., cols tx*4..
  const int ar = tid >> 2, ak = (tid & 3) << 2;  // A-load map
  float acc[4][4] = {{0.f, 0.f, 0.f, 0.f}, {0.f, 0.f, 0.f, 0.f},
                     {0.f, 0.f, 0.f, 0.f}, {0.f, 0.f, 0.f, 0.f}};
  for (int k0 = 0; k0 < K; k0 += 16) {
    float4 av = make_float4(0.f, 0.f, 0.f, 0.f);
    int grow = row0 + ar;
    if (grow < M) av = *(const float4*)(A + (size_t)grow * K + k0 + ak);
    As[ak + 0][ar] = av.x;
    As[ak + 1][ar] = av.y;
    As[ak + 2][ar] = av.z;
    As[ak + 3][ar] = av.w;
    float4 bv = *(const float4*)(B + (size_t)(k0 + ty) * N + col0 + (tx << 2));
    *(float4*)&Bs[ty][tx << 2] = bv;
    __syncthreads();
#pragma unroll
    for (int kk = 0; kk < 16; kk++) {
      float4 a = *(const float4*)&As[kk][ty << 2];
      float4 b = *(const float4*)&Bs[kk][tx << 2];
      acc[0][0] += a.x * b.x; acc[0][1] += a.x * b.y; acc[0][2] += a.x * b.z; acc[0][3] += a.x * b.w;
      acc[1][0] += a.y * b.x; acc[1][1] += a.y * b.y; acc[1][2] += a.y * b.z; acc[1][3] += a.y * b.w;
      acc[2][0] += a.z * b.x; acc[2][1] += a.z * b.y; acc[2][2] += a.z * b.z; acc[2][3] += a.z * b.w;
      acc[3][0] += a.w * b.x; acc[3][1] += a.w * b.y; acc[3][2] += a.w * b.z; acc[3][3] += a.w * b.w;
    }
    __syncthreads();
  }
#pragma unroll
  for (int i = 0; i < 4; i++) {
    int r = row0 + (ty << 2) + i;
    if (r < M) {
      float4 v = make_float4(acc[i][0], acc[i][1], acc[i][2], acc[i][3]);
      *(float4*)(C + (size_t)r * N + col0 + (tx << 2)) = v;
    }
  }
}

// ---------- per-(node,head) attention dots: el = <z, a_l>, er = <z, a_r> ----------
// z row length is 256 in both layers (heads*d = 256). One 64-lane wave per (n,h).
__global__ __launch_bounds__(256) void attn_dots(const float* __restrict__ z,
                                                 const float* __restrict__ al,
                                                 const float* __restrict__ ar,
                                                 float* __restrict__ el,
                                                 float* __restrict__ er,
                                                 int NH, int hshift, int d) {
  int wid = (blockIdx.x * 256 + threadIdx.x) >> 6;
  int lane = threadIdx.x & 63;
  if (wid >= NH) return;
  int h = wid & ((1 << hshift) - 1);
  int n = wid >> hshift;
  const float* zp = z + (size_t)n * 256 + h * d;
  const float* alp = al + h * d;
  const float* arp = ar + h * d;
  float pl = 0.f, pr = 0.f;
  for (int j = lane; j < d; j += 64) {
    float v = zp[j];
    pl += v * alp[j];
    pr += v * arp[j];
  }
#pragma unroll
  for (int o = 32; o > 0; o >>= 1) {
    pl += __shfl_down(pl, o);
    pr += __shfl_down(pr, o);
  }
  if (lane == 0) { el[wid] = pl; er[wid] = pr; }
}

// ---------- per-(edge,head): e = lrelu(el[src]+er[dst]); segment max via atomicMax ----------
__global__ __launch_bounds__(256) void edge_logits(const int* __restrict__ src,
                                                   const int* __restrict__ dst,
                                                   const float* __restrict__ el,
                                                   const float* __restrict__ er,
                                                   float* __restrict__ ebuf,
                                                   unsigned* __restrict__ mord,
                                                   int EH, int hshift) {
  int i = blockIdx.x * 256 + threadIdx.x;
  if (i >= EH) return;
  int e = i >> hshift, h = i & ((1 << hshift) - 1);
  int sn = src[e], dn = dst[e];
  float v = el[(sn << hshift) + h] + er[(dn << hshift) + h];
  v = (v > 0.f) ? v : 0.2f * v;
  ebuf[i] = v;
  atomicMax(&mord[(dn << hshift) + h], f2ord(v));
}

// ---------- per-(edge,head): ex = exp(e - m[dst]); segment sum via atomicAdd ----------
__global__ __launch_bounds__(256) void edge_expsum(const int* __restrict__ dst,
                                                   float* __restrict__ ebuf,
                                                   const unsigned* __restrict__ mord,
                                                   float* __restrict__ ssum,
                                                   int EH, int hshift) {
  int i = blockIdx.x * 256 + threadIdx.x;
  if (i >= EH) return;
  int e = i >> hshift, h = i & ((1 << hshift) - 1);
  int dn = dst[e];
  float m = ord2f(mord[(dn << hshift) + h]);
  float ex = expf(ebuf[i] - m);
  ebuf[i] = ex;
  atomicAdd(&ssum[(dn << hshift) + h], ex);
}

// ---------- weighted scatter-add: out[dst] += z[src] * alpha. One wave per edge ----------
__global__ __launch_bounds__(256) void edge_aggregate(const float* __restrict__ z,
                                                      const float* __restrict__ ebuf,
                                                      const float* __restrict__ ssum,
                                                      const int* __restrict__ src,
                                                      const int* __restrict__ dst,
                                                      float* __restrict__ out,
                                                      int Ecnt, int hshift, int dshift) {
  int wid = (blockIdx.x * 256 + threadIdx.x) >> 6;
  int lane = threadIdx.x & 63;
  if (wid >= Ecnt) return;
  int sn = src[wid], dn = dst[wid];
  float a0 = ebuf[(size_t)wid << hshift] / ssum[(size_t)dn << hshift];
  float a1 = hshift ? ebuf[((size_t)wid << hshift) + 1] / ssum[((size_t)dn << hshift) + 1] : a0;
  const float* zp = z + (size_t)sn * 256;
  float* op = out + (size_t)dn * 256;
#pragma unroll
  for (int c = 0; c < 4; c++) {
    int f = (c << 6) + lane;
    float alpha = (f >> dshift) ? a1 : a0;
    atomicAdd(&op[f], zp[f] * alpha);
  }
}

// ---------- x += bias (flat 256), optional relu; float4 over N*256 ----------
__global__ __launch_bounds__(256) void bias_act(float* __restrict__ xio,
                                                const float* __restrict__ b,
                                                int n4, int relu) {
  int i = blockIdx.x * 256 + threadIdx.x;
  if (i >= n4) return;
  float4 v = ((float4*)xio)[i];
  float4 bb = ((const float4*)b)[i & 63];
  v.x += bb.x; v.y += bb.y; v.z += bb.z; v.w += bb.w;
  if (relu) {
    v.x = fmaxf(v.x, 0.f); v.y = fmaxf(v.y, 0.f);
    v.z = fmaxf(v.z, 0.f); v.w = fmaxf(v.w, 0.f);
  }
  ((float4*)xio)[i] = v;
}

extern "C" void kernel_launch(void* const* d_in, const int* in_sizes, int n_in,
                              void* d_out, int out_size, void* d_ws, size_t ws_size,
                              hipStream_t stream) {
  const float* x   = (const float*)d_in[0];
  const int*   src = (const int*)d_in[1];
  const int*   dst = (const int*)d_in[2];
  const float* W1  = (const float*)d_in[3];
  const float* al1 = (const float*)d_in[4];
  const float* ar1 = (const float*)d_in[5];
  const float* b1  = (const float*)d_in[6];
  const float* W2  = (const float*)d_in[7];
  const float* al2 = (const float*)d_in[8];
  const float* ar2 = (const float*)d_in[9];
  const float* b2  = (const float*)d_in[10];
  float* out = (float*)d_out;
  (void)n_in; (void)out_size; (void)ws_size;

  const int Nn = in_sizes[0] / 256;  // 50000
  const int Ee = in_sizes[1];        // 800000
  const int F = 256;

  // workspace layout (floats); all region sizes keep 16B alignment
  float* ws    = (float*)d_ws;
  float* z     = ws;                              // Nn*256
  float* ebuf  = z + (size_t)Nn * F;              // Ee*2 (layer2 reuses first Ee)
  float* el1p  = ebuf + (size_t)Ee * 2;           // Nn*2
  float* er1p  = el1p + (size_t)Nn * 2;           // Nn*2
  unsigned* m1p = (unsigned*)(er1p + (size_t)Nn * 2);  // Nn*2
  float* s1p   = (float*)m1p + (size_t)Nn * 2;    // Nn*2
  float* el2p  = s1p + (size_t)Nn * 2;            // Nn
  float* er2p  = el2p + Nn;                       // Nn
  unsigned* m2p = (unsigned*)(er2p + Nn);         // Nn
  float* s2p   = (float*)m2p + Nn;                // Nn

  dim3 blk(256);
  const int nf4 = Nn * (F / 4);                   // Nn*64 float4 per feature array

  // init: agg1 (in d_out) = 0; m1+s1 = 0; m2+s2 = 0 (ordered-uint 0 < f2ord of any real)
  zero_f4<<<(nf4 + 255) / 256, blk, 0, stream>>>((float4*)out, nf4);
  zero_f4<<<(Nn + 255) / 256, blk, 0, stream>>>((float4*)m1p, Nn);          // 4*Nn floats
  zero_f4<<<(Nn / 2 + 255) / 256, blk, 0, stream>>>((float4*)m2p, Nn / 2);  // 2*Nn floats

  dim3 gg((Nn + 63) / 64, F / 64);

  // ---- layer 1 (heads=2, d=128) ----
  gemm_tile<<<gg, blk, 0, stream>>>(x, W1, z, Nn, F, 256);
  attn_dots<<<(Nn * 2 + 3) / 4, blk, 0, stream>>>(z, al1, ar1, el1p, er1p, Nn * 2, 1, 128);
  edge_logits<<<(Ee * 2 + 255) / 256, blk, 0, stream>>>(src, dst, el1p, er1p, ebuf, m1p, Ee * 2, 1);
  edge_expsum<<<(Ee * 2 + 255) / 256, blk, 0, stream>>>(dst, ebuf, m1p, s1p, Ee * 2, 1);
  edge_aggregate<<<(Ee + 3) / 4, blk, 0, stream>>>(z, ebuf, s1p, src, dst, out, Ee, 1, 7);
  bias_act<<<(nf4 + 255) / 256, blk, 0, stream>>>(out, b1, nf4, 1);  // h = relu(agg+b1)

  // ---- layer 2 (heads=1, d=256) ----
  gemm_tile<<<gg, blk, 0, stream>>>(out, W2, z, Nn, F, 256);  // z2 = h @ W2
  attn_dots<<<(Nn + 3) / 4, blk, 0, stream>>>(z, al2, ar2, el2p, er2p, Nn, 0, 256);
  edge_logits<<<(Ee + 255) / 256, blk, 0, stream>>>(src, dst, el2p, er2p, ebuf, m2p, Ee, 0);
  edge_expsum<<<(Ee + 255) / 256, blk, 0, stream>>>(dst, ebuf, m2p, s2p, Ee, 0);
  zero_f4<<<(nf4 + 255) / 256, blk, 0, stream>>>((float4*)out, nf4);  // h no longer needed
  edge_aggregate<<<(Ee + 3) / 4, blk, 0, stream>>>(z, ebuf, s2p, src, dst, out, Ee, 0, 8);
  bias_act<<<(nf4 + 255) / 256, blk, 0, stream>>>(out, b2, nf4, 0);
}

// Round 3
// 729.909 us; speedup vs baseline: 2.5185x; 2.5185x over previous
//
#include <hip/hip_runtime.h>
#include <math.h>

// Workspace: z (N*256 f32, 51.2MB) + esrc (E int, 3.2MB) + CSR arrays + el/er  ≈ 56 MB.

// ---------- zero fill (graph-capture-safe; also zeroes int arrays bitwise) ----------
__global__ __launch_bounds__(256) void zero_f4(float4* __restrict__ p, int n4) {
  int i = blockIdx.x * 256 + threadIdx.x;
  if (i < n4) p[i] = make_float4(0.f, 0.f, 0.f, 0.f);
}

// ---------- CSR build: histogram of dst ----------
__global__ __launch_bounds__(256) void hist_dst(const int* __restrict__ dst,
                                                int* __restrict__ counts, int E) {
  int i = blockIdx.x * 256 + threadIdx.x;
  if (i < E) atomicAdd(&counts[dst[i]], 1);
}

// ---------- CSR build: per-block exclusive scan (256 elems/block) ----------
__global__ __launch_bounds__(256) void scan_block(const int* __restrict__ counts,
                                                  int* __restrict__ offsets,
                                                  int* __restrict__ bsum, int Nn) {
  __shared__ int sm[256];
  int t = threadIdx.x;
  int i = blockIdx.x * 256 + t;
  int v = (i < Nn) ? counts[i] : 0;
  sm[t] = v;
  __syncthreads();
  for (int off = 1; off < 256; off <<= 1) {
    int x = (t >= off) ? sm[t - off] : 0;
    __syncthreads();
    sm[t] += x;
    __syncthreads();
  }
  if (i < Nn) offsets[i] = sm[t] - v;          // exclusive within block
  if (t == 255) bsum[blockIdx.x] = sm[255];    // block total
}

// ---------- CSR build: scan the block sums (single block; B <= 256) ----------
__global__ __launch_bounds__(256) void scan_bsum(int* __restrict__ bsum,
                                                 int* __restrict__ bofs, int B) {
  __shared__ int sm[256];
  int t = threadIdx.x;
  int v = (t < B) ? bsum[t] : 0;
  sm[t] = v;
  __syncthreads();
  for (int off = 1; off < 256; off <<= 1) {
    int x = (t >= off) ? sm[t - off] : 0;
    __syncthreads();
    sm[t] += x;
    __syncthreads();
  }
  if (t < B) bofs[t] = sm[t] - v;              // exclusive
}

// ---------- CSR build: add block offsets; init cursor ----------
__global__ __launch_bounds__(256) void scan_add(int* __restrict__ offsets,
                                                const int* __restrict__ bofs,
                                                int* __restrict__ cursor, int Nn) {
  int i = blockIdx.x * 256 + threadIdx.x;
  if (i < Nn) {
    int o = offsets[i] + bofs[i >> 8];
    offsets[i] = o;
    cursor[i] = o;
  }
}

// ---------- CSR build: scatter src ids sorted by dst ----------
__global__ __launch_bounds__(256) void scatter_edges(const int* __restrict__ src,
                                                     const int* __restrict__ dst,
                                                     int* __restrict__ cursor,
                                                     int* __restrict__ esrc, int E) {
  int i = blockIdx.x * 256 + threadIdx.x;
  if (i < E) {
    int pos = atomicAdd(&cursor[dst[i]], 1);
    esrc[pos] = src[i];
  }
}

// ---------- C[M,N] = A[M,K] @ B[K,N]; N,K multiples of 64/16; row-guard on M ----------
__global__ __launch_bounds__(256) void gemm_tile(const float* __restrict__ A,
                                                 const float* __restrict__ B,
                                                 float* __restrict__ C,
                                                 int M, int N, int K) {
  __shared__ float As[16][64];
  __shared__ float Bs[16][64];
  const int tid = threadIdx.x;
  const int row0 = blockIdx.x * 64;
  const int col0 = blockIdx.y * 64;
  const int ty = tid >> 4, tx = tid & 15;
  const int ar = tid >> 2, ak = (tid & 3) << 2;
  float acc[4][4] = {{0.f, 0.f, 0.f, 0.f}, {0.f, 0.f, 0.f, 0.f},
                     {0.f, 0.f, 0.f, 0.f}, {0.f, 0.f, 0.f, 0.f}};
  for (int k0 = 0; k0 < K; k0 += 16) {
    float4 av = make_float4(0.f, 0.f, 0.f, 0.f);
    int grow = row0 + ar;
    if (grow < M) av = *(const float4*)(A + (size_t)grow * K + k0 + ak);
    As[ak + 0][ar] = av.x;
    As[ak + 1][ar] = av.y;
    As[ak + 2][ar] = av.z;
    As[ak + 3][ar] = av.w;
    float4 bv = *(const float4*)(B + (size_t)(k0 + ty) * N + col0 + (tx << 2));
    *(float4*)&Bs[ty][tx << 2] = bv;
    __syncthreads();
#pragma unroll
    for (int kk = 0; kk < 16; kk++) {
      float4 a = *(const float4*)&As[kk][ty << 2];
      float4 b = *(const float4*)&Bs[kk][tx << 2];
      acc[0][0] += a.x * b.x; acc[0][1] += a.x * b.y; acc[0][2] += a.x * b.z; acc[0][3] += a.x * b.w;
      acc[1][0] += a.y * b.x; acc[1][1] += a.y * b.y; acc[1][2] += a.y * b.z; acc[1][3] += a.y * b.w;
      acc[2][0] += a.z * b.x; acc[2][1] += a.z * b.y; acc[2][2] += a.z * b.z; acc[2][3] += a.z * b.w;
      acc[3][0] += a.w * b.x; acc[3][1] += a.w * b.y; acc[3][2] += a.w * b.z; acc[3][3] += a.w * b.w;
    }
    __syncthreads();
  }
#pragma unroll
  for (int i = 0; i < 4; i++) {
    int r = row0 + (ty << 2) + i;
    if (r < M) {
      float4 v = make_float4(acc[i][0], acc[i][1], acc[i][2], acc[i][3]);
      *(float4*)(C + (size_t)r * N + col0 + (tx << 2)) = v;
    }
  }
}

// ---------- per-(node,head) attention dots: el = <z, a_l>, er = <z, a_r> ----------
__global__ __launch_bounds__(256) void attn_dots(const float* __restrict__ z,
                                                 const float* __restrict__ al,
                                                 const float* __restrict__ ar,
                                                 float* __restrict__ el,
                                                 float* __restrict__ er,
                                                 int NH, int hshift, int d) {
  int wid = (blockIdx.x * 256 + threadIdx.x) >> 6;
  int lane = threadIdx.x & 63;
  if (wid >= NH) return;
  int h = wid & ((1 << hshift) - 1);
  int n = wid >> hshift;
  const float* zp = z + (size_t)n * 256 + h * d;
  const float* alp = al + h * d;
  const float* arp = ar + h * d;
  float pl = 0.f, pr = 0.f;
  for (int j = lane; j < d; j += 64) {
    float v = zp[j];
    pl += v * alp[j];
    pr += v * arp[j];
  }
#pragma unroll
  for (int o = 32; o > 0; o >>= 1) {
    pl += __shfl_down(pl, o);
    pr += __shfl_down(pr, o);
  }
  if (lane == 0) { el[wid] = pl; er[wid] = pr; }
}

// ---------- fused per-node GAT: logits -> max -> exp/sum -> weighted agg -> bias/act ----------
// One 64-lane wave per dst node. H = 1<<hshift heads; dshift = log2(d).
__global__ __launch_bounds__(256) void node_aggregate(const float* __restrict__ z,
                                                      const float* __restrict__ el,
                                                      const float* __restrict__ er,
                                                      const int* __restrict__ esrc,
                                                      const int* __restrict__ offsets,
                                                      const int* __restrict__ counts,
                                                      const float* __restrict__ bias,
                                                      float* __restrict__ out,
                                                      int Nn, int hshift, int dshift,
                                                      int relu) {
  int n = (blockIdx.x * 256 + threadIdx.x) >> 6;
  int lane = threadIdx.x & 63;
  if (n >= Nn) return;
  int beg = offsets[n];
  int deg = counts[n];
  float ern0 = er[(size_t)n << hshift];
  float ern1 = hshift ? er[((size_t)n << hshift) + 1] : 0.f;

  // pass 1: lane-parallel segment max of lrelu(el[src]+er[n]) per head
  float mx0 = -INFINITY, mx1 = -INFINITY;
  for (int i = lane; i < deg; i += 64) {
    int sn = esrc[beg + i];
    float v0 = el[(size_t)sn << hshift] + ern0;
    v0 = (v0 > 0.f) ? v0 : 0.2f * v0;
    mx0 = fmaxf(mx0, v0);
    if (hshift) {
      float v1 = el[((size_t)sn << hshift) + 1] + ern1;
      v1 = (v1 > 0.f) ? v1 : 0.2f * v1;
      mx1 = fmaxf(mx1, v1);
    }
  }
#pragma unroll
  for (int o = 32; o > 0; o >>= 1) {
    mx0 = fmaxf(mx0, __shfl_xor(mx0, o));
    mx1 = fmaxf(mx1, __shfl_xor(mx1, o));
  }

  // per-lane head for its float4 chunk: elements 4*lane..4*lane+3 (never straddle d=128)
  int head = (lane << 2) >> dshift;

  // pass 2: sequential edges; ex broadcast-computed; acc += z[src]*ex
  float s0 = 0.f, s1 = 0.f;
  float4 acc = make_float4(0.f, 0.f, 0.f, 0.f);
  for (int i = 0; i < deg; i++) {
    int sn = esrc[beg + i];  // wave-uniform
    float v0 = el[(size_t)sn << hshift] + ern0;
    v0 = (v0 > 0.f) ? v0 : 0.2f * v0;
    float ex0 = __expf(v0 - mx0);
    s0 += ex0;
    float ex1 = ex0;
    if (hshift) {
      float v1 = el[((size_t)sn << hshift) + 1] + ern1;
      v1 = (v1 > 0.f) ? v1 : 0.2f * v1;
      ex1 = __expf(v1 - mx1);
      s1 += ex1;
    }
    float ex = head ? ex1 : ex0;
    float4 zv = ((const float4*)(z + ((size_t)sn << 8)))[lane];
    acc.x += zv.x * ex;
    acc.y += zv.y * ex;
    acc.z += zv.z * ex;
    acc.w += zv.w * ex;
  }

  // epilogue: normalize, add bias, optional relu, single coalesced store
  float s = head ? s1 : s0;
  float4 bb = ((const float4*)bias)[lane];
  float4 v;
  if (deg > 0) {
    float inv = 1.f / s;
    v = make_float4(acc.x * inv + bb.x, acc.y * inv + bb.y,
                    acc.z * inv + bb.z, acc.w * inv + bb.w);
  } else {
    v = bb;
  }
  if (relu) {
    v.x = fmaxf(v.x, 0.f); v.y = fmaxf(v.y, 0.f);
    v.z = fmaxf(v.z, 0.f); v.w = fmaxf(v.w, 0.f);
  }
  ((float4*)out)[((size_t)n << 6) + lane] = v;
}

extern "C" void kernel_launch(void* const* d_in, const int* in_sizes, int n_in,
                              void* d_out, int out_size, void* d_ws, size_t ws_size,
                              hipStream_t stream) {
  const float* x   = (const float*)d_in[0];
  const int*   src = (const int*)d_in[1];
  const int*   dst = (const int*)d_in[2];
  const float* W1  = (const float*)d_in[3];
  const float* al1 = (const float*)d_in[4];
  const float* ar1 = (const float*)d_in[5];
  const float* b1  = (const float*)d_in[6];
  const float* W2  = (const float*)d_in[7];
  const float* al2 = (const float*)d_in[8];
  const float* ar2 = (const float*)d_in[9];
  const float* b2  = (const float*)d_in[10];
  float* out = (float*)d_out;
  (void)n_in; (void)out_size; (void)ws_size;

  const int Nn = in_sizes[0] / 256;  // 50000
  const int Ee = in_sizes[1];        // 800000
  const int F = 256;
  const int NB = (Nn + 255) / 256;   // scan blocks (196 <= 256)

  // workspace layout
  float* ws     = (float*)d_ws;
  float* z      = ws;                               // Nn*256 f32
  int*   esrc   = (int*)(z + (size_t)Nn * F);       // Ee
  int*   counts = esrc + Ee;                        // Nn
  int*   offs   = counts + Nn;                      // Nn
  int*   cursor = offs + Nn;                        // Nn
  int*   bsum   = cursor + Nn;                      // 256
  int*   bofs   = bsum + 256;                       // 256
  float* el1p   = (float*)(bofs + 256);             // Nn*2
  float* er1p   = el1p + (size_t)Nn * 2;            // Nn*2
  float* el2p   = er1p + (size_t)Nn * 2;            // Nn
  float* er2p   = el2p + Nn;                        // Nn

  dim3 blk(256);

  // ---- CSR build (once, shared by both layers) ----
  zero_f4<<<(Nn / 4 + 255) / 256, blk, 0, stream>>>((float4*)counts, Nn / 4);
  hist_dst<<<(Ee + 255) / 256, blk, 0, stream>>>(dst, counts, Ee);
  scan_block<<<NB, blk, 0, stream>>>(counts, offs, bsum, Nn);
  scan_bsum<<<1, blk, 0, stream>>>(bsum, bofs, NB);
  scan_add<<<NB, blk, 0, stream>>>(offs, bofs, cursor, Nn);
  scatter_edges<<<(Ee + 255) / 256, blk, 0, stream>>>(src, dst, cursor, esrc, Ee);

  dim3 gg((Nn + 63) / 64, F / 64);

  // ---- layer 1 (heads=2, d=128) ----
  gemm_tile<<<gg, blk, 0, stream>>>(x, W1, z, Nn, F, 256);
  attn_dots<<<(Nn * 2 + 3) / 4, blk, 0, stream>>>(z, al1, ar1, el1p, er1p, Nn * 2, 1, 128);
  node_aggregate<<<(Nn + 3) / 4, blk, 0, stream>>>(z, el1p, er1p, esrc, offs, counts,
                                                   b1, out, Nn, 1, 7, 1);

  // ---- layer 2 (heads=1, d=256) ----
  gemm_tile<<<gg, blk, 0, stream>>>(out, W2, z, Nn, F, 256);  // z2 = h @ W2
  attn_dots<<<(Nn + 3) / 4, blk, 0, stream>>>(z, al2, ar2, el2p, er2p, Nn, 0, 256);
  node_aggregate<<<(Nn + 3) / 4, blk, 0, stream>>>(z, el2p, er2p, esrc, offs, counts,
                                                   b2, out, Nn, 0, 8, 0);
}

// Round 4
// 668.864 us; speedup vs baseline: 2.7484x; 1.0913x over previous
//
#include <hip/hip_runtime.h>
#include <math.h>

// Workspace: z (N*256 f32, 51.2MB) + esrc (E int) + CSR arrays + el/er  ≈ 56 MB.

// ---------- zero fill (graph-capture-safe) ----------
__global__ __launch_bounds__(256) void zero_f4(float4* __restrict__ p, int n4) {
  int i = blockIdx.x * 256 + threadIdx.x;
  if (i < n4) p[i] = make_float4(0.f, 0.f, 0.f, 0.f);
}

// ---------- CSR build ----------
__global__ __launch_bounds__(256) void hist_dst(const int* __restrict__ dst,
                                                int* __restrict__ counts, int E) {
  int i = blockIdx.x * 256 + threadIdx.x;
  if (i < E) atomicAdd(&counts[dst[i]], 1);
}

__global__ __launch_bounds__(256) void scan_block(const int* __restrict__ counts,
                                                  int* __restrict__ offsets,
                                                  int* __restrict__ bsum, int Nn) {
  __shared__ int sm[256];
  int t = threadIdx.x;
  int i = blockIdx.x * 256 + t;
  int v = (i < Nn) ? counts[i] : 0;
  sm[t] = v;
  __syncthreads();
  for (int off = 1; off < 256; off <<= 1) {
    int x = (t >= off) ? sm[t - off] : 0;
    __syncthreads();
    sm[t] += x;
    __syncthreads();
  }
  if (i < Nn) offsets[i] = sm[t] - v;
  if (t == 255) bsum[blockIdx.x] = sm[255];
}

__global__ __launch_bounds__(256) void scan_bsum(int* __restrict__ bsum,
                                                 int* __restrict__ bofs, int B) {
  __shared__ int sm[256];
  int t = threadIdx.x;
  int v = (t < B) ? bsum[t] : 0;
  sm[t] = v;
  __syncthreads();
  for (int off = 1; off < 256; off <<= 1) {
    int x = (t >= off) ? sm[t - off] : 0;
    __syncthreads();
    sm[t] += x;
    __syncthreads();
  }
  if (t < B) bofs[t] = sm[t] - v;
}

__global__ __launch_bounds__(256) void scan_add(int* __restrict__ offsets,
                                                const int* __restrict__ bofs,
                                                int* __restrict__ cursor, int Nn) {
  int i = blockIdx.x * 256 + threadIdx.x;
  if (i < Nn) {
    int o = offsets[i] + bofs[i >> 8];
    offsets[i] = o;
    cursor[i] = o;
  }
}

__global__ __launch_bounds__(256) void scatter_edges(const int* __restrict__ src,
                                                     const int* __restrict__ dst,
                                                     int* __restrict__ cursor,
                                                     int* __restrict__ esrc, int E) {
  int i = blockIdx.x * 256 + threadIdx.x;
  if (i < E) {
    int pos = atomicAdd(&cursor[dst[i]], 1);
    esrc[pos] = src[i];
  }
}

// ---------- C[M,N] = A[M,K] @ B[K,N] ----------
__global__ __launch_bounds__(256) void gemm_tile(const float* __restrict__ A,
                                                 const float* __restrict__ B,
                                                 float* __restrict__ C,
                                                 int M, int N, int K) {
  __shared__ float As[16][64];
  __shared__ float Bs[16][64];
  const int tid = threadIdx.x;
  const int row0 = blockIdx.x * 64;
  const int col0 = blockIdx.y * 64;
  const int ty = tid >> 4, tx = tid & 15;
  const int ar = tid >> 2, ak = (tid & 3) << 2;
  float acc[4][4] = {{0.f, 0.f, 0.f, 0.f}, {0.f, 0.f, 0.f, 0.f},
                     {0.f, 0.f, 0.f, 0.f}, {0.f, 0.f, 0.f, 0.f}};
  for (int k0 = 0; k0 < K; k0 += 16) {
    float4 av = make_float4(0.f, 0.f, 0.f, 0.f);
    int grow = row0 + ar;
    if (grow < M) av = *(const float4*)(A + (size_t)grow * K + k0 + ak);
    As[ak + 0][ar] = av.x;
    As[ak + 1][ar] = av.y;
    As[ak + 2][ar] = av.z;
    As[ak + 3][ar] = av.w;
    float4 bv = *(const float4*)(B + (size_t)(k0 + ty) * N + col0 + (tx << 2));
    *(float4*)&Bs[ty][tx << 2] = bv;
    __syncthreads();
#pragma unroll
    for (int kk = 0; kk < 16; kk++) {
      float4 a = *(const float4*)&As[kk][ty << 2];
      float4 b = *(const float4*)&Bs[kk][tx << 2];
      acc[0][0] += a.x * b.x; acc[0][1] += a.x * b.y; acc[0][2] += a.x * b.z; acc[0][3] += a.x * b.w;
      acc[1][0] += a.y * b.x; acc[1][1] += a.y * b.y; acc[1][2] += a.y * b.z; acc[1][3] += a.y * b.w;
      acc[2][0] += a.z * b.x; acc[2][1] += a.z * b.y; acc[2][2] += a.z * b.z; acc[2][3] += a.z * b.w;
      acc[3][0] += a.w * b.x; acc[3][1] += a.w * b.y; acc[3][2] += a.w * b.z; acc[3][3] += a.w * b.w;
    }
    __syncthreads();
  }
#pragma unroll
  for (int i = 0; i < 4; i++) {
    int r = row0 + (ty << 2) + i;
    if (r < M) {
      float4 v = make_float4(acc[i][0], acc[i][1], acc[i][2], acc[i][3]);
      *(float4*)(C + (size_t)r * N + col0 + (tx << 2)) = v;
    }
  }
}

// ---------- per-(node,head) attention dots ----------
__global__ __launch_bounds__(256) void attn_dots(const float* __restrict__ z,
                                                 const float* __restrict__ al,
                                                 const float* __restrict__ ar,
                                                 float* __restrict__ el,
                                                 float* __restrict__ er,
                                                 int NH, int hshift, int d) {
  int wid = (blockIdx.x * 256 + threadIdx.x) >> 6;
  int lane = threadIdx.x & 63;
  if (wid >= NH) return;
  int h = wid & ((1 << hshift) - 1);
  int n = wid >> hshift;
  const float* zp = z + (size_t)n * 256 + h * d;
  const float* alp = al + h * d;
  const float* arp = ar + h * d;
  float pl = 0.f, pr = 0.f;
  for (int j = lane; j < d; j += 64) {
    float v = zp[j];
    pl += v * alp[j];
    pr += v * arp[j];
  }
#pragma unroll
  for (int o = 32; o > 0; o >>= 1) {
    pl += __shfl_down(pl, o);
    pr += __shfl_down(pr, o);
  }
  if (lane == 0) { el[wid] = pl; er[wid] = pr; }
}

// ---------- fused per-node GAT, flash-style online softmax over 64-edge chunks ----------
// One 64-lane wave per dst node. HS: 1 if 2 heads; DS = log2(d); RELU epilogue flag.
// Inner loop: zero memory traffic except the z row gather (shuffle-broadcast sn/ex).
template <int HS, int DS, int RELU>
__global__ __launch_bounds__(256) void node_aggregate(const float* __restrict__ z,
                                                      const float* __restrict__ el,
                                                      const float* __restrict__ er,
                                                      const int* __restrict__ esrc,
                                                      const int* __restrict__ offsets,
                                                      const int* __restrict__ counts,
                                                      const float* __restrict__ bias,
                                                      float* __restrict__ out, int Nn) {
  int n = (blockIdx.x * 256 + threadIdx.x) >> 6;
  int lane = threadIdx.x & 63;
  if (n >= Nn) return;
  const int beg = offsets[n];
  const int deg = counts[n];
  float ern0, ern1 = 0.f;
  if (HS) {
    float2 e = ((const float2*)er)[n];
    ern0 = e.x; ern1 = e.y;
  } else {
    ern0 = er[n];
  }
  const int head = HS ? ((lane << 2) >> DS) : 0;  // this lane's float4 chunk's head

  float m0 = -INFINITY, m1 = -INFINITY;  // running max per head
  float s0p = 0.f, s1p = 0.f;            // per-lane partial denom per head
  float4 acc = make_float4(0.f, 0.f, 0.f, 0.f);

  for (int base = 0; base < deg; base += 64) {
    const int cnt = min(64, deg - base);
    int sn = 0;
    float v0 = -INFINITY, v1 = -INFINITY;
    if (lane < cnt) {
      sn = esrc[beg + base + lane];
      if (HS) {
        float2 elv = ((const float2*)el)[sn];
        v0 = elv.x + ern0; v0 = (v0 > 0.f) ? v0 : 0.2f * v0;
        v1 = elv.y + ern1; v1 = (v1 > 0.f) ? v1 : 0.2f * v1;
      } else {
        v0 = el[sn] + ern0; v0 = (v0 > 0.f) ? v0 : 0.2f * v0;
      }
    }
    // chunk max
    float cm0 = v0, cm1 = v1;
#pragma unroll
    for (int o = 32; o > 0; o >>= 1) {
      cm0 = fmaxf(cm0, __shfl_xor(cm0, o));
      if (HS) cm1 = fmaxf(cm1, __shfl_xor(cm1, o));
    }
    const float nm0 = fmaxf(m0, cm0);
    const float sc0 = __expf(m0 - nm0);  // first chunk: exp(-inf)=0, state was 0 anyway
    float nm1 = nm0, sc1 = sc0;
    if (HS) { nm1 = fmaxf(m1, cm1); sc1 = __expf(m1 - nm1); }
    s0p = s0p * sc0;
    const float myex0 = __expf(v0 - nm0);  // inactive lanes: exp(-inf)=0
    s0p += myex0;
    float myex1 = 0.f;
    if (HS) { s1p = s1p * sc1; myex1 = __expf(v1 - nm1); s1p += myex1; }
    const float sch = (HS && head) ? sc1 : sc0;
    acc.x *= sch; acc.y *= sch; acc.z *= sch; acc.w *= sch;
    m0 = nm0; m1 = nm1;

    // gather+accumulate, 4 edges in flight
    int i = 0;
    for (; i + 4 <= cnt; i += 4) {
      int sa = __shfl(sn, i + 0), sb = __shfl(sn, i + 1);
      int sc_ = __shfl(sn, i + 2), sd = __shfl(sn, i + 3);
      float ea = __shfl(myex0, i + 0), eb = __shfl(myex0, i + 1);
      float ec = __shfl(myex0, i + 2), ed = __shfl(myex0, i + 3);
      if (HS) {
        float ea1 = __shfl(myex1, i + 0), eb1 = __shfl(myex1, i + 1);
        float ec1 = __shfl(myex1, i + 2), ed1 = __shfl(myex1, i + 3);
        if (head) { ea = ea1; eb = eb1; ec = ec1; ed = ed1; }
      }
      float4 za = ((const float4*)(z + ((size_t)sa << 8)))[lane];
      float4 zb = ((const float4*)(z + ((size_t)sb << 8)))[lane];
      float4 zc = ((const float4*)(z + ((size_t)sc_ << 8)))[lane];
      float4 zd = ((const float4*)(z + ((size_t)sd << 8)))[lane];
      acc.x += za.x * ea; acc.y += za.y * ea; acc.z += za.z * ea; acc.w += za.w * ea;
      acc.x += zb.x * eb; acc.y += zb.y * eb; acc.z += zb.z * eb; acc.w += zb.w * eb;
      acc.x += zc.x * ec; acc.y += zc.y * ec; acc.z += zc.z * ec; acc.w += zc.w * ec;
      acc.x += zd.x * ed; acc.y += zd.y * ed; acc.z += zd.z * ed; acc.w += zd.w * ed;
    }
    for (; i < cnt; i++) {
      int si = __shfl(sn, i);
      float e = __shfl(myex0, i);
      if (HS) {
        float e1 = __shfl(myex1, i);
        if (head) e = e1;
      }
      float4 zv = ((const float4*)(z + ((size_t)si << 8)))[lane];
      acc.x += zv.x * e; acc.y += zv.y * e; acc.z += zv.z * e; acc.w += zv.w * e;
    }
  }

  // reduce denominators across wave
#pragma unroll
  for (int o = 32; o > 0; o >>= 1) {
    s0p += __shfl_xor(s0p, o);
    if (HS) s1p += __shfl_xor(s1p, o);
  }
  const float s = (HS && head) ? s1p : s0p;
  float4 bb = ((const float4*)bias)[lane];
  float4 v;
  if (deg > 0) {
    float inv = 1.f / s;
    v = make_float4(acc.x * inv + bb.x, acc.y * inv + bb.y,
                    acc.z * inv + bb.z, acc.w * inv + bb.w);
  } else {
    v = bb;
  }
  if (RELU) {
    v.x = fmaxf(v.x, 0.f); v.y = fmaxf(v.y, 0.f);
    v.z = fmaxf(v.z, 0.f); v.w = fmaxf(v.w, 0.f);
  }
  ((float4*)out)[((size_t)n << 6) + lane] = v;
}

extern "C" void kernel_launch(void* const* d_in, const int* in_sizes, int n_in,
                              void* d_out, int out_size, void* d_ws, size_t ws_size,
                              hipStream_t stream) {
  const float* x   = (const float*)d_in[0];
  const int*   src = (const int*)d_in[1];
  const int*   dst = (const int*)d_in[2];
  const float* W1  = (const float*)d_in[3];
  const float* al1 = (const float*)d_in[4];
  const float* ar1 = (const float*)d_in[5];
  const float* b1  = (const float*)d_in[6];
  const float* W2  = (const float*)d_in[7];
  const float* al2 = (const float*)d_in[8];
  const float* ar2 = (const float*)d_in[9];
  const float* b2  = (const float*)d_in[10];
  float* out = (float*)d_out;
  (void)n_in; (void)out_size; (void)ws_size;

  const int Nn = in_sizes[0] / 256;  // 50000
  const int Ee = in_sizes[1];        // 800000
  const int F = 256;
  const int NB = (Nn + 255) / 256;

  // workspace layout
  float* ws     = (float*)d_ws;
  float* z      = ws;                               // Nn*256 f32
  int*   esrc   = (int*)(z + (size_t)Nn * F);       // Ee
  int*   counts = esrc + Ee;                        // Nn
  int*   offs   = counts + Nn;                      // Nn
  int*   cursor = offs + Nn;                        // Nn
  int*   bsum   = cursor + Nn;                      // 256
  int*   bofs   = bsum + 256;                       // 256
  float* el1p   = (float*)(bofs + 256);             // Nn*2
  float* er1p   = el1p + (size_t)Nn * 2;            // Nn*2
  float* el2p   = er1p + (size_t)Nn * 2;            // Nn
  float* er2p   = el2p + Nn;                        // Nn

  dim3 blk(256);

  // ---- CSR build (once, shared by both layers) ----
  zero_f4<<<(Nn / 4 + 255) / 256, blk, 0, stream>>>((float4*)counts, Nn / 4);
  hist_dst<<<(Ee + 255) / 256, blk, 0, stream>>>(dst, counts, Ee);
  scan_block<<<NB, blk, 0, stream>>>(counts, offs, bsum, Nn);
  scan_bsum<<<1, blk, 0, stream>>>(bsum, bofs, NB);
  scan_add<<<NB, blk, 0, stream>>>(offs, bofs, cursor, Nn);
  scatter_edges<<<(Ee + 255) / 256, blk, 0, stream>>>(src, dst, cursor, esrc, Ee);

  dim3 gg((Nn + 63) / 64, F / 64);

  // ---- layer 1 (heads=2, d=128) ----
  gemm_tile<<<gg, blk, 0, stream>>>(x, W1, z, Nn, F, 256);
  attn_dots<<<(Nn * 2 + 3) / 4, blk, 0, stream>>>(z, al1, ar1, el1p, er1p, Nn * 2, 1, 128);
  node_aggregate<1, 7, 1><<<(Nn + 3) / 4, blk, 0, stream>>>(z, el1p, er1p, esrc, offs,
                                                            counts, b1, out, Nn);

  // ---- layer 2 (heads=1, d=256) ----
  gemm_tile<<<gg, blk, 0, stream>>>(out, W2, z, Nn, F, 256);  // z2 = h @ W2
  attn_dots<<<(Nn + 3) / 4, blk, 0, stream>>>(z, al2, ar2, el2p, er2p, Nn, 0, 256);
  node_aggregate<0, 8, 0><<<(Nn + 3) / 4, blk, 0, stream>>>(z, el2p, er2p, esrc, offs,
                                                            counts, b2, out, Nn);
}

// Round 5
// 648.170 us; speedup vs baseline: 2.8361x; 1.0319x over previous
//
#include <hip/hip_runtime.h>
#include <math.h>

// Workspace: z (N*256 f32, 51.2MB) + esrc (E int) + CSR arrays + el/er  ≈ 56 MB.

__device__ __forceinline__ float rl_f(float x, int i) {
  return __int_as_float(__builtin_amdgcn_readlane(__float_as_int(x), i));
}

// ---------- zero fill (graph-capture-safe) ----------
__global__ __launch_bounds__(256) void zero_f4(float4* __restrict__ p, int n4) {
  int i = blockIdx.x * 256 + threadIdx.x;
  if (i < n4) p[i] = make_float4(0.f, 0.f, 0.f, 0.f);
}

// ---------- CSR build ----------
__global__ __launch_bounds__(256) void hist_dst(const int* __restrict__ dst,
                                                int* __restrict__ counts, int E) {
  int i = blockIdx.x * 256 + threadIdx.x;
  if (i < E) atomicAdd(&counts[dst[i]], 1);
}

__global__ __launch_bounds__(256) void scan_block(const int* __restrict__ counts,
                                                  int* __restrict__ offsets,
                                                  int* __restrict__ bsum, int Nn) {
  __shared__ int sm[256];
  int t = threadIdx.x;
  int i = blockIdx.x * 256 + t;
  int v = (i < Nn) ? counts[i] : 0;
  sm[t] = v;
  __syncthreads();
  for (int off = 1; off < 256; off <<= 1) {
    int x = (t >= off) ? sm[t - off] : 0;
    __syncthreads();
    sm[t] += x;
    __syncthreads();
  }
  if (i < Nn) offsets[i] = sm[t] - v;
  if (t == 255) bsum[blockIdx.x] = sm[255];
}

__global__ __launch_bounds__(256) void scan_bsum(int* __restrict__ bsum,
                                                 int* __restrict__ bofs, int B) {
  __shared__ int sm[256];
  int t = threadIdx.x;
  int v = (t < B) ? bsum[t] : 0;
  sm[t] = v;
  __syncthreads();
  for (int off = 1; off < 256; off <<= 1) {
    int x = (t >= off) ? sm[t - off] : 0;
    __syncthreads();
    sm[t] += x;
    __syncthreads();
  }
  if (t < B) bofs[t] = sm[t] - v;
}

__global__ __launch_bounds__(256) void scan_add(int* __restrict__ offsets,
                                                const int* __restrict__ bofs,
                                                int* __restrict__ cursor, int Nn) {
  int i = blockIdx.x * 256 + threadIdx.x;
  if (i < Nn) {
    int o = offsets[i] + bofs[i >> 8];
    offsets[i] = o;
    cursor[i] = o;
  }
}

__global__ __launch_bounds__(256) void scatter_edges(const int* __restrict__ src,
                                                     const int* __restrict__ dst,
                                                     int* __restrict__ cursor,
                                                     int* __restrict__ esrc, int E) {
  int i = blockIdx.x * 256 + threadIdx.x;
  if (i < E) {
    int pos = atomicAdd(&cursor[dst[i]], 1);
    esrc[pos] = src[i];
  }
}

// ---------- C[M,N] = A[M,K] @ B[K,N]; 64x128 tile, 4x8 microtile ----------
__global__ __launch_bounds__(256) void gemm_tile(const float* __restrict__ A,
                                                 const float* __restrict__ B,
                                                 float* __restrict__ C,
                                                 int M, int N, int K) {
  __shared__ float As[16][64];
  __shared__ float Bs[16][128];
  const int tid = threadIdx.x;
  const int row0 = blockIdx.x * 64;
  const int col0 = blockIdx.y * 128;
  const int ty = tid >> 4, tx = tid & 15;        // compute: rows ty*4.., cols tx*8..
  const int ar = tid >> 2, ak = (tid & 3) << 2;  // A load: row ar, k ak..ak+3
  const int by = tid >> 5, bx = (tid & 31) << 2; // B load: rows by,by+8; col bx..bx+3
  float acc[4][8];
#pragma unroll
  for (int i = 0; i < 4; i++)
#pragma unroll
    for (int j = 0; j < 8; j++) acc[i][j] = 0.f;

  for (int k0 = 0; k0 < K; k0 += 16) {
    float4 av = make_float4(0.f, 0.f, 0.f, 0.f);
    int grow = row0 + ar;
    if (grow < M) av = *(const float4*)(A + (size_t)grow * K + k0 + ak);
    As[ak + 0][ar] = av.x;
    As[ak + 1][ar] = av.y;
    As[ak + 2][ar] = av.z;
    As[ak + 3][ar] = av.w;
    float4 bv0 = *(const float4*)(B + (size_t)(k0 + by) * N + col0 + bx);
    float4 bv1 = *(const float4*)(B + (size_t)(k0 + by + 8) * N + col0 + bx);
    *(float4*)&Bs[by][bx] = bv0;
    *(float4*)&Bs[by + 8][bx] = bv1;
    __syncthreads();
#pragma unroll
    for (int kk = 0; kk < 16; kk++) {
      float4 a = *(const float4*)&As[kk][ty << 2];
      float4 b0 = *(const float4*)&Bs[kk][tx << 3];
      float4 b1 = *(const float4*)&Bs[kk][(tx << 3) + 4];
      float ax[4] = {a.x, a.y, a.z, a.w};
      float bxv[8] = {b0.x, b0.y, b0.z, b0.w, b1.x, b1.y, b1.z, b1.w};
#pragma unroll
      for (int i = 0; i < 4; i++)
#pragma unroll
        for (int j = 0; j < 8; j++) acc[i][j] += ax[i] * bxv[j];
    }
    __syncthreads();
  }
#pragma unroll
  for (int i = 0; i < 4; i++) {
    int r = row0 + (ty << 2) + i;
    if (r < M) {
      float4 v0 = make_float4(acc[i][0], acc[i][1], acc[i][2], acc[i][3]);
      float4 v1 = make_float4(acc[i][4], acc[i][5], acc[i][6], acc[i][7]);
      *(float4*)(C + (size_t)r * N + col0 + (tx << 3)) = v0;
      *(float4*)(C + (size_t)r * N + col0 + (tx << 3) + 4) = v1;
    }
  }
}

// ---------- per-(node,head) attention dots ----------
__global__ __launch_bounds__(256) void attn_dots(const float* __restrict__ z,
                                                 const float* __restrict__ al,
                                                 const float* __restrict__ ar,
                                                 float* __restrict__ el,
                                                 float* __restrict__ er,
                                                 int NH, int hshift, int d) {
  int wid = (blockIdx.x * 256 + threadIdx.x) >> 6;
  int lane = threadIdx.x & 63;
  if (wid >= NH) return;
  int h = wid & ((1 << hshift) - 1);
  int n = wid >> hshift;
  const float* zp = z + (size_t)n * 256 + h * d;
  const float* alp = al + h * d;
  const float* arp = ar + h * d;
  float pl = 0.f, pr = 0.f;
  for (int j = lane; j < d; j += 64) {
    float v = zp[j];
    pl += v * alp[j];
    pr += v * arp[j];
  }
#pragma unroll
  for (int o = 32; o > 0; o >>= 1) {
    pl += __shfl_down(pl, o);
    pr += __shfl_down(pr, o);
  }
  if (lane == 0) { el[wid] = pl; er[wid] = pr; }
}

// ---------- fused per-node GAT, flash-style online softmax over 64-edge chunks ----------
// One 64-lane wave per dst node. Inner gather loop: readlane broadcast (VALU, no LDS),
// 8 independent z-row loads in flight.
template <int HS, int DS, int RELU>
__global__ __launch_bounds__(256) void node_aggregate(const float* __restrict__ z,
                                                      const float* __restrict__ el,
                                                      const float* __restrict__ er,
                                                      const int* __restrict__ esrc,
                                                      const int* __restrict__ offsets,
                                                      const int* __restrict__ counts,
                                                      const float* __restrict__ bias,
                                                      float* __restrict__ out, int Nn) {
  int n = (blockIdx.x * 256 + threadIdx.x) >> 6;
  int lane = threadIdx.x & 63;
  if (n >= Nn) return;
  const int beg = offsets[n];
  const int deg = counts[n];
  float ern0, ern1 = 0.f;
  if (HS) {
    float2 e = ((const float2*)er)[n];
    ern0 = e.x; ern1 = e.y;
  } else {
    ern0 = er[n];
  }
  const int head = HS ? ((lane << 2) >> DS) : 0;  // this lane's float4 chunk's head

  float m0 = -INFINITY, m1 = -INFINITY;
  float s0p = 0.f, s1p = 0.f;
  float4 acc = make_float4(0.f, 0.f, 0.f, 0.f);

  for (int base = 0; base < deg; base += 64) {
    const int cnt = min(64, deg - base);
    int sn = 0;
    float v0 = -INFINITY, v1 = -INFINITY;
    if (lane < cnt) {
      sn = esrc[beg + base + lane];
      if (HS) {
        float2 elv = ((const float2*)el)[sn];
        v0 = elv.x + ern0; v0 = (v0 > 0.f) ? v0 : 0.2f * v0;
        v1 = elv.y + ern1; v1 = (v1 > 0.f) ? v1 : 0.2f * v1;
      } else {
        v0 = el[sn] + ern0; v0 = (v0 > 0.f) ? v0 : 0.2f * v0;
      }
    }
    // chunk max (once per 64 edges; shuffles OK here)
    float cm0 = v0, cm1 = v1;
#pragma unroll
    for (int o = 32; o > 0; o >>= 1) {
      cm0 = fmaxf(cm0, __shfl_xor(cm0, o));
      if (HS) cm1 = fmaxf(cm1, __shfl_xor(cm1, o));
    }
    const float nm0 = fmaxf(m0, cm0);
    const float sc0 = __expf(m0 - nm0);  // first chunk: exp(-inf)=0, state was 0
    float nm1 = nm0, sc1 = sc0;
    if (HS) { nm1 = fmaxf(m1, cm1); sc1 = __expf(m1 - nm1); }
    s0p = s0p * sc0;
    const float myex0 = __expf(v0 - nm0);  // inactive lanes: exp(-inf)=0
    s0p += myex0;
    float myex1 = 0.f;
    if (HS) { s1p = s1p * sc1; myex1 = __expf(v1 - nm1); s1p += myex1; }
    const float sch = (HS && head) ? sc1 : sc0;
    acc.x *= sch; acc.y *= sch; acc.z *= sch; acc.w *= sch;
    m0 = nm0; m1 = nm1;

    // gather+accumulate: readlane broadcast, 8 loads in flight
    int i = 0;
    for (; i + 8 <= cnt; i += 8) {
      int s_[8];
      float e_[8];
      float4 zv[8];
#pragma unroll
      for (int j = 0; j < 8; j++) {
        s_[j] = __builtin_amdgcn_readlane(sn, i + j);
        float e0 = rl_f(myex0, i + j);
        if (HS) {
          float e1 = rl_f(myex1, i + j);
          e_[j] = head ? e1 : e0;
        } else {
          e_[j] = e0;
        }
      }
#pragma unroll
      for (int j = 0; j < 8; j++)
        zv[j] = ((const float4*)(z + ((size_t)s_[j] << 8)))[lane];
#pragma unroll
      for (int j = 0; j < 8; j++) {
        acc.x += zv[j].x * e_[j];
        acc.y += zv[j].y * e_[j];
        acc.z += zv[j].z * e_[j];
        acc.w += zv[j].w * e_[j];
      }
    }
    for (; i < cnt; i++) {
      int si = __builtin_amdgcn_readlane(sn, i);
      float e = rl_f(myex0, i);
      if (HS) {
        float e1 = rl_f(myex1, i);
        if (head) e = e1;
      }
      float4 zv = ((const float4*)(z + ((size_t)si << 8)))[lane];
      acc.x += zv.x * e; acc.y += zv.y * e; acc.z += zv.z * e; acc.w += zv.w * e;
    }
  }

  // reduce denominators across wave
#pragma unroll
  for (int o = 32; o > 0; o >>= 1) {
    s0p += __shfl_xor(s0p, o);
    if (HS) s1p += __shfl_xor(s1p, o);
  }
  const float s = (HS && head) ? s1p : s0p;
  float4 bb = ((const float4*)bias)[lane];
  float4 v;
  if (deg > 0) {
    float inv = 1.f / s;
    v = make_float4(acc.x * inv + bb.x, acc.y * inv + bb.y,
                    acc.z * inv + bb.z, acc.w * inv + bb.w);
  } else {
    v = bb;
  }
  if (RELU) {
    v.x = fmaxf(v.x, 0.f); v.y = fmaxf(v.y, 0.f);
    v.z = fmaxf(v.z, 0.f); v.w = fmaxf(v.w, 0.f);
  }
  ((float4*)out)[((size_t)n << 6) + lane] = v;
}

extern "C" void kernel_launch(void* const* d_in, const int* in_sizes, int n_in,
                              void* d_out, int out_size, void* d_ws, size_t ws_size,
                              hipStream_t stream) {
  const float* x   = (const float*)d_in[0];
  const int*   src = (const int*)d_in[1];
  const int*   dst = (const int*)d_in[2];
  const float* W1  = (const float*)d_in[3];
  const float* al1 = (const float*)d_in[4];
  const float* ar1 = (const float*)d_in[5];
  const float* b1  = (const float*)d_in[6];
  const float* W2  = (const float*)d_in[7];
  const float* al2 = (const float*)d_in[8];
  const float* ar2 = (const float*)d_in[9];
  const float* b2  = (const float*)d_in[10];
  float* out = (float*)d_out;
  (void)n_in; (void)out_size; (void)ws_size;

  const int Nn = in_sizes[0] / 256;  // 50000
  const int Ee = in_sizes[1];        // 800000
  const int F = 256;
  const int NB = (Nn + 255) / 256;

  // workspace layout
  float* ws     = (float*)d_ws;
  float* z      = ws;                               // Nn*256 f32
  int*   esrc   = (int*)(z + (size_t)Nn * F);       // Ee
  int*   counts = esrc + Ee;                        // Nn
  int*   offs   = counts + Nn;                      // Nn
  int*   cursor = offs + Nn;                        // Nn
  int*   bsum   = cursor + Nn;                      // 256
  int*   bofs   = bsum + 256;                       // 256
  float* el1p   = (float*)(bofs + 256);             // Nn*2
  float* er1p   = el1p + (size_t)Nn * 2;            // Nn*2
  float* el2p   = er1p + (size_t)Nn * 2;            // Nn
  float* er2p   = el2p + Nn;                        // Nn

  dim3 blk(256);

  // ---- CSR build (once, shared by both layers) ----
  zero_f4<<<(Nn / 4 + 255) / 256, blk, 0, stream>>>((float4*)counts, Nn / 4);
  hist_dst<<<(Ee + 255) / 256, blk, 0, stream>>>(dst, counts, Ee);
  scan_block<<<NB, blk, 0, stream>>>(counts, offs, bsum, Nn);
  scan_bsum<<<1, blk, 0, stream>>>(bsum, bofs, NB);
  scan_add<<<NB, blk, 0, stream>>>(offs, bofs, cursor, Nn);
  scatter_edges<<<(Ee + 255) / 256, blk, 0, stream>>>(src, dst, cursor, esrc, Ee);

  dim3 gg((Nn + 63) / 64, F / 128);

  // ---- layer 1 (heads=2, d=128) ----
  gemm_tile<<<gg, blk, 0, stream>>>(x, W1, z, Nn, F, 256);
  attn_dots<<<(Nn * 2 + 3) / 4, blk, 0, stream>>>(z, al1, ar1, el1p, er1p, Nn * 2, 1, 128);
  node_aggregate<1, 7, 1><<<(Nn + 3) / 4, blk, 0, stream>>>(z, el1p, er1p, esrc, offs,
                                                            counts, b1, out, Nn);

  // ---- layer 2 (heads=1, d=256) ----
  gemm_tile<<<gg, blk, 0, stream>>>(out, W2, z, Nn, F, 256);  // z2 = h @ W2
  attn_dots<<<(Nn + 3) / 4, blk, 0, stream>>>(z, al2, ar2, el2p, er2p, Nn, 0, 256);
  node_aggregate<0, 8, 0><<<(Nn + 3) / 4, blk, 0, stream>>>(z, el2p, er2p, esrc, offs,
                                                            counts, b2, out, Nn);
}

// Round 6
// 546.309 us; speedup vs baseline: 3.3649x; 1.1865x over previous
//
#include <hip/hip_runtime.h>
#include <hip/hip_fp16.h>
#include <math.h>

// Workspace: z (N*256 f16, 25.6MB) + esrc (E int) + CSR arrays + el/er  ≈ 31 MB.

__device__ __forceinline__ float rl_f(float x, int i) {
  return __int_as_float(__builtin_amdgcn_readlane(__float_as_int(x), i));
}
__device__ __forceinline__ float cvt_h(unsigned u) {  // low 16 bits: fp16 -> fp32
  return __half2float(__ushort_as_half((unsigned short)(u & 0xffffu)));
}
__device__ __forceinline__ unsigned pk2(float a, float b) {  // 2x fp32 -> packed fp16
  return (unsigned)__half_as_ushort(__float2half_rn(a)) |
         ((unsigned)__half_as_ushort(__float2half_rn(b)) << 16);
}

// ---------- zero fill (graph-capture-safe) ----------
__global__ __launch_bounds__(256) void zero_f4(float4* __restrict__ p, int n4) {
  int i = blockIdx.x * 256 + threadIdx.x;
  if (i < n4) p[i] = make_float4(0.f, 0.f, 0.f, 0.f);
}

// ---------- CSR build ----------
__global__ __launch_bounds__(256) void hist_dst(const int* __restrict__ dst,
                                                int* __restrict__ counts, int E) {
  int i = blockIdx.x * 256 + threadIdx.x;
  if (i < E) atomicAdd(&counts[dst[i]], 1);
}

__global__ __launch_bounds__(256) void scan_block(const int* __restrict__ counts,
                                                  int* __restrict__ offsets,
                                                  int* __restrict__ bsum, int Nn) {
  __shared__ int sm[256];
  int t = threadIdx.x;
  int i = blockIdx.x * 256 + t;
  int v = (i < Nn) ? counts[i] : 0;
  sm[t] = v;
  __syncthreads();
  for (int off = 1; off < 256; off <<= 1) {
    int x = (t >= off) ? sm[t - off] : 0;
    __syncthreads();
    sm[t] += x;
    __syncthreads();
  }
  if (i < Nn) offsets[i] = sm[t] - v;
  if (t == 255) bsum[blockIdx.x] = sm[255];
}

__global__ __launch_bounds__(256) void scan_bsum(int* __restrict__ bsum,
                                                 int* __restrict__ bofs, int B) {
  __shared__ int sm[256];
  int t = threadIdx.x;
  int v = (t < B) ? bsum[t] : 0;
  sm[t] = v;
  __syncthreads();
  for (int off = 1; off < 256; off <<= 1) {
    int x = (t >= off) ? sm[t - off] : 0;
    __syncthreads();
    sm[t] += x;
    __syncthreads();
  }
  if (t < B) bofs[t] = sm[t] - v;
}

__global__ __launch_bounds__(256) void scan_add(int* __restrict__ offsets,
                                                const int* __restrict__ bofs,
                                                int* __restrict__ cursor, int Nn) {
  int i = blockIdx.x * 256 + threadIdx.x;
  if (i < Nn) {
    int o = offsets[i] + bofs[i >> 8];
    offsets[i] = o;
    cursor[i] = o;
  }
}

__global__ __launch_bounds__(256) void scatter_edges(const int* __restrict__ src,
                                                     const int* __restrict__ dst,
                                                     int* __restrict__ cursor,
                                                     int* __restrict__ esrc, int E) {
  int i = blockIdx.x * 256 + threadIdx.x;
  if (i < E) {
    int pos = atomicAdd(&cursor[dst[i]], 1);
    esrc[pos] = src[i];
  }
}

// ---------- C[M,N] = A[M,K] @ B[K,N]; fp32 compute, fp16 packed output ----------
// 64x128 tile, 4x8 microtile. N,K multiples of 128/16.
__global__ __launch_bounds__(256) void gemm_tile(const float* __restrict__ A,
                                                 const float* __restrict__ B,
                                                 unsigned short* __restrict__ C,
                                                 int M, int N, int K) {
  __shared__ float As[16][64];
  __shared__ float Bs[16][128];
  const int tid = threadIdx.x;
  const int row0 = blockIdx.x * 64;
  const int col0 = blockIdx.y * 128;
  const int ty = tid >> 4, tx = tid & 15;        // compute: rows ty*4.., cols tx*8..
  const int ar = tid >> 2, ak = (tid & 3) << 2;  // A load: row ar, k ak..ak+3
  const int by = tid >> 5, bx = (tid & 31) << 2; // B load: rows by,by+8; col bx..bx+3
  float acc[4][8];
#pragma unroll
  for (int i = 0; i < 4; i++)
#pragma unroll
    for (int j = 0; j < 8; j++) acc[i][j] = 0.f;

  for (int k0 = 0; k0 < K; k0 += 16) {
    float4 av = make_float4(0.f, 0.f, 0.f, 0.f);
    int grow = row0 + ar;
    if (grow < M) av = *(const float4*)(A + (size_t)grow * K + k0 + ak);
    As[ak + 0][ar] = av.x;
    As[ak + 1][ar] = av.y;
    As[ak + 2][ar] = av.z;
    As[ak + 3][ar] = av.w;
    float4 bv0 = *(const float4*)(B + (size_t)(k0 + by) * N + col0 + bx);
    float4 bv1 = *(const float4*)(B + (size_t)(k0 + by + 8) * N + col0 + bx);
    *(float4*)&Bs[by][bx] = bv0;
    *(float4*)&Bs[by + 8][bx] = bv1;
    __syncthreads();
#pragma unroll
    for (int kk = 0; kk < 16; kk++) {
      float4 a = *(const float4*)&As[kk][ty << 2];
      float4 b0 = *(const float4*)&Bs[kk][tx << 3];
      float4 b1 = *(const float4*)&Bs[kk][(tx << 3) + 4];
      float ax[4] = {a.x, a.y, a.z, a.w};
      float bxv[8] = {b0.x, b0.y, b0.z, b0.w, b1.x, b1.y, b1.z, b1.w};
#pragma unroll
      for (int i = 0; i < 4; i++)
#pragma unroll
        for (int j = 0; j < 8; j++) acc[i][j] += ax[i] * bxv[j];
    }
    __syncthreads();
  }
#pragma unroll
  for (int i = 0; i < 4; i++) {
    int r = row0 + (ty << 2) + i;
    if (r < M) {
      uint4 o;
      o.x = pk2(acc[i][0], acc[i][1]);
      o.y = pk2(acc[i][2], acc[i][3]);
      o.z = pk2(acc[i][4], acc[i][5]);
      o.w = pk2(acc[i][6], acc[i][7]);
      *(uint4*)(C + (size_t)r * N + col0 + (tx << 3)) = o;
    }
  }
}

// ---------- per-(node,head) attention dots (z in fp16) ----------
__global__ __launch_bounds__(256) void attn_dots(const unsigned short* __restrict__ z,
                                                 const float* __restrict__ al,
                                                 const float* __restrict__ ar,
                                                 float* __restrict__ el,
                                                 float* __restrict__ er,
                                                 int NH, int hshift, int d) {
  int wid = (blockIdx.x * 256 + threadIdx.x) >> 6;
  int lane = threadIdx.x & 63;
  if (wid >= NH) return;
  int h = wid & ((1 << hshift) - 1);
  int n = wid >> hshift;
  const unsigned short* zp = z + (size_t)n * 256 + h * d;
  const float* alp = al + h * d;
  const float* arp = ar + h * d;
  float pl = 0.f, pr = 0.f;
  for (int j0 = lane * 2; j0 < d; j0 += 128) {
    unsigned u = *(const unsigned*)(zp + j0);
    float f0 = cvt_h(u), f1 = cvt_h(u >> 16);
    pl += f0 * alp[j0] + f1 * alp[j0 + 1];
    pr += f0 * arp[j0] + f1 * arp[j0 + 1];
  }
#pragma unroll
  for (int o = 32; o > 0; o >>= 1) {
    pl += __shfl_down(pl, o);
    pr += __shfl_down(pr, o);
  }
  if (lane == 0) { el[wid] = pl; er[wid] = pr; }
}

// ---------- fused per-node GAT, flash-style online softmax over 64-edge chunks ----------
// One 64-lane wave per dst node; z rows gathered as fp16 (uint2 = 4 halves / lane).
template <int HS, int DS, int RELU>
__global__ __launch_bounds__(256) void node_aggregate(const unsigned short* __restrict__ z,
                                                      const float* __restrict__ el,
                                                      const float* __restrict__ er,
                                                      const int* __restrict__ esrc,
                                                      const int* __restrict__ offsets,
                                                      const int* __restrict__ counts,
                                                      const float* __restrict__ bias,
                                                      float* __restrict__ out, int Nn) {
  int n = (blockIdx.x * 256 + threadIdx.x) >> 6;
  int lane = threadIdx.x & 63;
  if (n >= Nn) return;
  const int beg = offsets[n];
  const int deg = counts[n];
  float ern0, ern1 = 0.f;
  if (HS) {
    float2 e = ((const float2*)er)[n];
    ern0 = e.x; ern1 = e.y;
  } else {
    ern0 = er[n];
  }
  const int head = HS ? ((lane << 2) >> DS) : 0;  // this lane's 4-feat chunk's head

  float m0 = -INFINITY, m1 = -INFINITY;
  float s0p = 0.f, s1p = 0.f;
  float4 acc = make_float4(0.f, 0.f, 0.f, 0.f);

  for (int base = 0; base < deg; base += 64) {
    const int cnt = min(64, deg - base);
    int sn = 0;
    float v0 = -INFINITY, v1 = -INFINITY;
    if (lane < cnt) {
      sn = esrc[beg + base + lane];
      if (HS) {
        float2 elv = ((const float2*)el)[sn];
        v0 = elv.x + ern0; v0 = (v0 > 0.f) ? v0 : 0.2f * v0;
        v1 = elv.y + ern1; v1 = (v1 > 0.f) ? v1 : 0.2f * v1;
      } else {
        v0 = el[sn] + ern0; v0 = (v0 > 0.f) ? v0 : 0.2f * v0;
      }
    }
    // chunk max
    float cm0 = v0, cm1 = v1;
#pragma unroll
    for (int o = 32; o > 0; o >>= 1) {
      cm0 = fmaxf(cm0, __shfl_xor(cm0, o));
      if (HS) cm1 = fmaxf(cm1, __shfl_xor(cm1, o));
    }
    const float nm0 = fmaxf(m0, cm0);
    const float sc0 = __expf(m0 - nm0);  // first chunk: exp(-inf)=0, state was 0
    float nm1 = nm0, sc1 = sc0;
    if (HS) { nm1 = fmaxf(m1, cm1); sc1 = __expf(m1 - nm1); }
    s0p = s0p * sc0;
    const float myex0 = __expf(v0 - nm0);
    s0p += myex0;
    float myex1 = 0.f;
    if (HS) { s1p = s1p * sc1; myex1 = __expf(v1 - nm1); s1p += myex1; }
    const float sch = (HS && head) ? sc1 : sc0;
    acc.x *= sch; acc.y *= sch; acc.z *= sch; acc.w *= sch;
    m0 = nm0; m1 = nm1;

    // gather+accumulate: readlane broadcast, 8 fp16 row-loads in flight
    int i = 0;
    for (; i + 8 <= cnt; i += 8) {
      int s_[8];
      float e_[8];
      uint2 zv[8];
#pragma unroll
      for (int j = 0; j < 8; j++) {
        s_[j] = __builtin_amdgcn_readlane(sn, i + j);
        float e0 = rl_f(myex0, i + j);
        if (HS) {
          float e1 = rl_f(myex1, i + j);
          e_[j] = head ? e1 : e0;
        } else {
          e_[j] = e0;
        }
      }
#pragma unroll
      for (int j = 0; j < 8; j++)
        zv[j] = ((const uint2*)(z + ((size_t)s_[j] << 8)))[lane];
#pragma unroll
      for (int j = 0; j < 8; j++) {
        acc.x += cvt_h(zv[j].x) * e_[j];
        acc.y += cvt_h(zv[j].x >> 16) * e_[j];
        acc.z += cvt_h(zv[j].y) * e_[j];
        acc.w += cvt_h(zv[j].y >> 16) * e_[j];
      }
    }
    for (; i < cnt; i++) {
      int si = __builtin_amdgcn_readlane(sn, i);
      float e = rl_f(myex0, i);
      if (HS) {
        float e1 = rl_f(myex1, i);
        if (head) e = e1;
      }
      uint2 zv = ((const uint2*)(z + ((size_t)si << 8)))[lane];
      acc.x += cvt_h(zv.x) * e;
      acc.y += cvt_h(zv.x >> 16) * e;
      acc.z += cvt_h(zv.y) * e;
      acc.w += cvt_h(zv.y >> 16) * e;
    }
  }

  // reduce denominators across wave
#pragma unroll
  for (int o = 32; o > 0; o >>= 1) {
    s0p += __shfl_xor(s0p, o);
    if (HS) s1p += __shfl_xor(s1p, o);
  }
  const float s = (HS && head) ? s1p : s0p;
  float4 bb = ((const float4*)bias)[lane];
  float4 v;
  if (deg > 0) {
    float inv = 1.f / s;
    v = make_float4(acc.x * inv + bb.x, acc.y * inv + bb.y,
                    acc.z * inv + bb.z, acc.w * inv + bb.w);
  } else {
    v = bb;
  }
  if (RELU) {
    v.x = fmaxf(v.x, 0.f); v.y = fmaxf(v.y, 0.f);
    v.z = fmaxf(v.z, 0.f); v.w = fmaxf(v.w, 0.f);
  }
  ((float4*)out)[((size_t)n << 6) + lane] = v;
}

extern "C" void kernel_launch(void* const* d_in, const int* in_sizes, int n_in,
                              void* d_out, int out_size, void* d_ws, size_t ws_size,
                              hipStream_t stream) {
  const float* x   = (const float*)d_in[0];
  const int*   src = (const int*)d_in[1];
  const int*   dst = (const int*)d_in[2];
  const float* W1  = (const float*)d_in[3];
  const float* al1 = (const float*)d_in[4];
  const float* ar1 = (const float*)d_in[5];
  const float* b1  = (const float*)d_in[6];
  const float* W2  = (const float*)d_in[7];
  const float* al2 = (const float*)d_in[8];
  const float* ar2 = (const float*)d_in[9];
  const float* b2  = (const float*)d_in[10];
  float* out = (float*)d_out;
  (void)n_in; (void)out_size; (void)ws_size;

  const int Nn = in_sizes[0] / 256;  // 50000
  const int Ee = in_sizes[1];        // 800000
  const int F = 256;
  const int NB = (Nn + 255) / 256;

  // workspace layout
  unsigned short* z = (unsigned short*)d_ws;        // Nn*256 f16
  int*   esrc   = (int*)(z + (size_t)Nn * F);       // Ee
  int*   counts = esrc + Ee;                        // Nn
  int*   offs   = counts + Nn;                      // Nn
  int*   cursor = offs + Nn;                        // Nn
  int*   bsum   = cursor + Nn;                      // 256
  int*   bofs   = bsum + 256;                       // 256
  float* el1p   = (float*)(bofs + 256);             // Nn*2
  float* er1p   = el1p + (size_t)Nn * 2;            // Nn*2
  float* el2p   = er1p + (size_t)Nn * 2;            // Nn
  float* er2p   = el2p + Nn;                        // Nn

  dim3 blk(256);

  // ---- CSR build (once, shared by both layers) ----
  zero_f4<<<(Nn / 4 + 255) / 256, blk, 0, stream>>>((float4*)counts, Nn / 4);
  hist_dst<<<(Ee + 255) / 256, blk, 0, stream>>>(dst, counts, Ee);
  scan_block<<<NB, blk, 0, stream>>>(counts, offs, bsum, Nn);
  scan_bsum<<<1, blk, 0, stream>>>(bsum, bofs, NB);
  scan_add<<<NB, blk, 0, stream>>>(offs, bofs, cursor, Nn);
  scatter_edges<<<(Ee + 255) / 256, blk, 0, stream>>>(src, dst, cursor, esrc, Ee);

  dim3 gg((Nn + 63) / 64, F / 128);

  // ---- layer 1 (heads=2, d=128) ----
  gemm_tile<<<gg, blk, 0, stream>>>(x, W1, z, Nn, F, 256);
  attn_dots<<<(Nn * 2 + 3) / 4, blk, 0, stream>>>(z, al1, ar1, el1p, er1p, Nn * 2, 1, 128);
  node_aggregate<1, 7, 1><<<(Nn + 3) / 4, blk, 0, stream>>>(z, el1p, er1p, esrc, offs,
                                                            counts, b1, out, Nn);

  // ---- layer 2 (heads=1, d=256) ----
  gemm_tile<<<gg, blk, 0, stream>>>(out, W2, z, Nn, F, 256);  // z2 = h @ W2
  attn_dots<<<(Nn + 3) / 4, blk, 0, stream>>>(z, al2, ar2, el2p, er2p, Nn, 0, 256);
  node_aggregate<0, 8, 0><<<(Nn + 3) / 4, blk, 0, stream>>>(z, el2p, er2p, esrc, offs,
                                                            counts, b2, out, Nn);
}

// Round 7
// 496.263 us; speedup vs baseline: 3.7043x; 1.1008x over previous
//
#include <hip/hip_runtime.h>
#include <hip/hip_fp16.h>
#include <math.h>

// Workspace (halves unless noted): z (Nn*256) + xh/hh (Nn*256, aliased) + W1t/W2t
// (256*256 each) + esrc (E int) + CSR ints + el/er floats  ≈ 56 MB.

typedef _Float16 half8 __attribute__((ext_vector_type(8)));
typedef float floatx4 __attribute__((ext_vector_type(4)));

__device__ __forceinline__ float rl_f(float x, int i) {
  return __int_as_float(__builtin_amdgcn_readlane(__float_as_int(x), i));
}
__device__ __forceinline__ float cvt_h(unsigned u) {  // low 16 bits: fp16 -> fp32
  return __half2float(__ushort_as_half((unsigned short)(u & 0xffffu)));
}
__device__ __forceinline__ unsigned pk2(float a, float b) {  // 2x fp32 -> packed fp16
  return (unsigned)__half_as_ushort(__float2half_rn(a)) |
         ((unsigned)__half_as_ushort(__float2half_rn(b)) << 16);
}

// ---------- zero fill ----------
__global__ __launch_bounds__(256) void zero_f4(float4* __restrict__ p, int n4) {
  int i = blockIdx.x * 256 + threadIdx.x;
  if (i < n4) p[i] = make_float4(0.f, 0.f, 0.f, 0.f);
}

// ---------- fp32 -> fp16 bulk convert (4 elems/thread) ----------
__global__ __launch_bounds__(256) void cvt_half(const float4* __restrict__ in,
                                                uint2* __restrict__ outh, int n4) {
  int i = blockIdx.x * 256 + threadIdx.x;
  if (i < n4) {
    float4 v = in[i];
    uint2 o;
    o.x = pk2(v.x, v.y);
    o.y = pk2(v.z, v.w);
    outh[i] = o;
  }
}

// ---------- W [256,256] fp32 -> Wt [256,256] fp16 transposed ----------
// blockIdx = k, thread = n: coalesced read of W row k.
__global__ __launch_bounds__(256) void transpose_w(const float* __restrict__ W,
                                                   unsigned short* __restrict__ Wt) {
  int k = blockIdx.x, n = threadIdx.x;
  Wt[n * 256 + k] = __half_as_ushort(__float2half_rn(W[k * 256 + n]));
}

// ---------- CSR build ----------
__global__ __launch_bounds__(256) void hist_dst(const int* __restrict__ dst,
                                                int* __restrict__ counts, int E) {
  int i = blockIdx.x * 256 + threadIdx.x;
  if (i < E) atomicAdd(&counts[dst[i]], 1);
}

__global__ __launch_bounds__(256) void scan_block(const int* __restrict__ counts,
                                                  int* __restrict__ offsets,
                                                  int* __restrict__ bsum, int Nn) {
  __shared__ int sm[256];
  int t = threadIdx.x;
  int i = blockIdx.x * 256 + t;
  int v = (i < Nn) ? counts[i] : 0;
  sm[t] = v;
  __syncthreads();
  for (int off = 1; off < 256; off <<= 1) {
    int x = (t >= off) ? sm[t - off] : 0;
    __syncthreads();
    sm[t] += x;
    __syncthreads();
  }
  if (i < Nn) offsets[i] = sm[t] - v;
  if (t == 255) bsum[blockIdx.x] = sm[255];
}

__global__ __launch_bounds__(256) void scan_bsum(int* __restrict__ bsum,
                                                 int* __restrict__ bofs, int B) {
  __shared__ int sm[256];
  int t = threadIdx.x;
  int v = (t < B) ? bsum[t] : 0;
  sm[t] = v;
  __syncthreads();
  for (int off = 1; off < 256; off <<= 1) {
    int x = (t >= off) ? sm[t - off] : 0;
    __syncthreads();
    sm[t] += x;
    __syncthreads();
  }
  if (t < B) bofs[t] = sm[t] - v;
}

__global__ __launch_bounds__(256) void scan_add(int* __restrict__ offsets,
                                                const int* __restrict__ bofs,
                                                int* __restrict__ cursor, int Nn) {
  int i = blockIdx.x * 256 + threadIdx.x;
  if (i < Nn) {
    int o = offsets[i] + bofs[i >> 8];
    offsets[i] = o;
    cursor[i] = o;
  }
}

__global__ __launch_bounds__(256) void scatter_edges(const int* __restrict__ src,
                                                     const int* __restrict__ dst,
                                                     int* __restrict__ cursor,
                                                     int* __restrict__ esrc, int E) {
  int i = blockIdx.x * 256 + threadIdx.x;
  if (i < E) {
    int pos = atomicAdd(&cursor[dst[i]], 1);
    esrc[pos] = src[i];
  }
}

// ---------- MFMA GEMM: C[M,256] = A[M,256] @ Wt^T, all fp16 storage, fp32 accum ----
// A fp16 [M,K=256] row-major; Wt fp16 [N=256,K=256] row-major (pre-transposed W).
// Block = 4 waves; wave w owns rows r0=64*bx+16w .. +15, all 256 cols (16 MFMA tiles).
// Operand swap: mfma(bfrag, afrag) computes C^T in C/D layout => each lane holds 4
// consecutive C columns of one row => one packed uint2 (4 fp16) store per tile.
__global__ __launch_bounds__(256) void gemm_mfma(const unsigned short* __restrict__ A,
                                                 const unsigned short* __restrict__ Wt,
                                                 unsigned short* __restrict__ C, int M) {
  const int tid = threadIdx.x;
  const int wv = tid >> 6, lane = tid & 63;
  const int ln = lane & 15, kg = lane >> 4;           // ln: row/col in tile, kg: k-group
  const int r0 = blockIdx.x * 64 + wv * 16;
  const int row = r0 + ln;
  const int rr = (row < M) ? row : (M - 1);           // clamp OOB rows (never stored)

  floatx4 acc[16];
#pragma unroll
  for (int t = 0; t < 16; t++) acc[t] = (floatx4)0.f;

  const unsigned short* ap = A + (size_t)rr * 256 + kg * 8;
#pragma unroll
  for (int kb = 0; kb < 256; kb += 32) {
    half8 af = *(const half8*)(ap + kb);              // A[rr][kb+kg*8 ..+7]
#pragma unroll
    for (int t = 0; t < 16; t++) {
      half8 bf = *(const half8*)(Wt + (size_t)(t * 16 + ln) * 256 + kb + kg * 8);
      acc[t] = __builtin_amdgcn_mfma_f32_16x16x32_f16(bf, af, acc[t], 0, 0, 0);
    }
  }

  if (row < M) {
    unsigned short* cp = C + (size_t)row * 256 + kg * 4;
#pragma unroll
    for (int t = 0; t < 16; t++) {
      uint2 o;
      o.x = pk2(acc[t].x, acc[t].y);
      o.y = pk2(acc[t].z, acc[t].w);
      *(uint2*)(cp + t * 16) = o;
    }
  }
}

// ---------- per-(node,head) attention dots (z in fp16) ----------
__global__ __launch_bounds__(256) void attn_dots(const unsigned short* __restrict__ z,
                                                 const float* __restrict__ al,
                                                 const float* __restrict__ ar,
                                                 float* __restrict__ el,
                                                 float* __restrict__ er,
                                                 int NH, int hshift, int d) {
  int wid = (blockIdx.x * 256 + threadIdx.x) >> 6;
  int lane = threadIdx.x & 63;
  if (wid >= NH) return;
  int h = wid & ((1 << hshift) - 1);
  int n = wid >> hshift;
  const unsigned short* zp = z + (size_t)n * 256 + h * d;
  const float* alp = al + h * d;
  const float* arp = ar + h * d;
  float pl = 0.f, pr = 0.f;
  for (int j0 = lane * 2; j0 < d; j0 += 128) {
    unsigned u = *(const unsigned*)(zp + j0);
    float f0 = cvt_h(u), f1 = cvt_h(u >> 16);
    pl += f0 * alp[j0] + f1 * alp[j0 + 1];
    pr += f0 * arp[j0] + f1 * arp[j0 + 1];
  }
#pragma unroll
  for (int o = 32; o > 0; o >>= 1) {
    pl += __shfl_down(pl, o);
    pr += __shfl_down(pr, o);
  }
  if (lane == 0) { el[wid] = pl; er[wid] = pr; }
}

// ---------- fused per-node GAT, flash-style online softmax over 64-edge chunks ------
// One wave per dst node; z gathered as fp16 (uint2/lane). OUTH: write fp16 h rows.
template <int HS, int DS, int RELU, int OUTH>
__global__ __launch_bounds__(256) void node_aggregate(const unsigned short* __restrict__ z,
                                                      const float* __restrict__ el,
                                                      const float* __restrict__ er,
                                                      const int* __restrict__ esrc,
                                                      const int* __restrict__ offsets,
                                                      const int* __restrict__ counts,
                                                      const float* __restrict__ bias,
                                                      void* __restrict__ out, int Nn) {
  int n = (blockIdx.x * 256 + threadIdx.x) >> 6;
  int lane = threadIdx.x & 63;
  if (n >= Nn) return;
  const int beg = offsets[n];
  const int deg = counts[n];
  float ern0, ern1 = 0.f;
  if (HS) {
    float2 e = ((const float2*)er)[n];
    ern0 = e.x; ern1 = e.y;
  } else {
    ern0 = er[n];
  }
  const int head = HS ? ((lane << 2) >> DS) : 0;

  float m0 = -INFINITY, m1 = -INFINITY;
  float s0p = 0.f, s1p = 0.f;
  float4 acc = make_float4(0.f, 0.f, 0.f, 0.f);

  for (int base = 0; base < deg; base += 64) {
    const int cnt = min(64, deg - base);
    int sn = 0;
    float v0 = -INFINITY, v1 = -INFINITY;
    if (lane < cnt) {
      sn = esrc[beg + base + lane];
      if (HS) {
        float2 elv = ((const float2*)el)[sn];
        v0 = elv.x + ern0; v0 = (v0 > 0.f) ? v0 : 0.2f * v0;
        v1 = elv.y + ern1; v1 = (v1 > 0.f) ? v1 : 0.2f * v1;
      } else {
        v0 = el[sn] + ern0; v0 = (v0 > 0.f) ? v0 : 0.2f * v0;
      }
    }
    float cm0 = v0, cm1 = v1;
#pragma unroll
    for (int o = 32; o > 0; o >>= 1) {
      cm0 = fmaxf(cm0, __shfl_xor(cm0, o));
      if (HS) cm1 = fmaxf(cm1, __shfl_xor(cm1, o));
    }
    const float nm0 = fmaxf(m0, cm0);
    const float sc0 = __expf(m0 - nm0);
    float nm1 = nm0, sc1 = sc0;
    if (HS) { nm1 = fmaxf(m1, cm1); sc1 = __expf(m1 - nm1); }
    s0p = s0p * sc0;
    const float myex0 = __expf(v0 - nm0);
    s0p += myex0;
    float myex1 = 0.f;
    if (HS) { s1p = s1p * sc1; myex1 = __expf(v1 - nm1); s1p += myex1; }
    const float sch = (HS && head) ? sc1 : sc0;
    acc.x *= sch; acc.y *= sch; acc.z *= sch; acc.w *= sch;
    m0 = nm0; m1 = nm1;

    int i = 0;
    for (; i + 8 <= cnt; i += 8) {
      int s_[8];
      float e_[8];
      uint2 zv[8];
#pragma unroll
      for (int j = 0; j < 8; j++) {
        s_[j] = __builtin_amdgcn_readlane(sn, i + j);
        float e0 = rl_f(myex0, i + j);
        if (HS) {
          float e1 = rl_f(myex1, i + j);
          e_[j] = head ? e1 : e0;
        } else {
          e_[j] = e0;
        }
      }
#pragma unroll
      for (int j = 0; j < 8; j++)
        zv[j] = ((const uint2*)(z + ((size_t)s_[j] << 8)))[lane];
#pragma unroll
      for (int j = 0; j < 8; j++) {
        acc.x += cvt_h(zv[j].x) * e_[j];
        acc.y += cvt_h(zv[j].x >> 16) * e_[j];
        acc.z += cvt_h(zv[j].y) * e_[j];
        acc.w += cvt_h(zv[j].y >> 16) * e_[j];
      }
    }
    for (; i < cnt; i++) {
      int si = __builtin_amdgcn_readlane(sn, i);
      float e = rl_f(myex0, i);
      if (HS) {
        float e1 = rl_f(myex1, i);
        if (head) e = e1;
      }
      uint2 zv = ((const uint2*)(z + ((size_t)si << 8)))[lane];
      acc.x += cvt_h(zv.x) * e;
      acc.y += cvt_h(zv.x >> 16) * e;
      acc.z += cvt_h(zv.y) * e;
      acc.w += cvt_h(zv.y >> 16) * e;
    }
  }

#pragma unroll
  for (int o = 32; o > 0; o >>= 1) {
    s0p += __shfl_xor(s0p, o);
    if (HS) s1p += __shfl_xor(s1p, o);
  }
  const float s = (HS && head) ? s1p : s0p;
  float4 bb = ((const float4*)bias)[lane];
  float4 v;
  if (deg > 0) {
    float inv = 1.f / s;
    v = make_float4(acc.x * inv + bb.x, acc.y * inv + bb.y,
                    acc.z * inv + bb.z, acc.w * inv + bb.w);
  } else {
    v = bb;
  }
  if (RELU) {
    v.x = fmaxf(v.x, 0.f); v.y = fmaxf(v.y, 0.f);
    v.z = fmaxf(v.z, 0.f); v.w = fmaxf(v.w, 0.f);
  }
  if (OUTH) {
    uint2 o;
    o.x = pk2(v.x, v.y);
    o.y = pk2(v.z, v.w);
    ((uint2*)out)[((size_t)n << 6) + lane] = o;
  } else {
    ((float4*)out)[((size_t)n << 6) + lane] = v;
  }
}

extern "C" void kernel_launch(void* const* d_in, const int* in_sizes, int n_in,
                              void* d_out, int out_size, void* d_ws, size_t ws_size,
                              hipStream_t stream) {
  const float* x   = (const float*)d_in[0];
  const int*   src = (const int*)d_in[1];
  const int*   dst = (const int*)d_in[2];
  const float* W1  = (const float*)d_in[3];
  const float* al1 = (const float*)d_in[4];
  const float* ar1 = (const float*)d_in[5];
  const float* b1  = (const float*)d_in[6];
  const float* W2  = (const float*)d_in[7];
  const float* al2 = (const float*)d_in[8];
  const float* ar2 = (const float*)d_in[9];
  const float* b2  = (const float*)d_in[10];
  float* out = (float*)d_out;
  (void)n_in; (void)out_size; (void)ws_size;

  const int Nn = in_sizes[0] / 256;  // 50000
  const int Ee = in_sizes[1];        // 800000
  const int F = 256;
  const int NB = (Nn + 255) / 256;

  // workspace layout
  unsigned short* z   = (unsigned short*)d_ws;      // Nn*256 fp16
  unsigned short* xh  = z + (size_t)Nn * F;         // Nn*256 fp16 (reused as hh)
  unsigned short* w1t = xh + (size_t)Nn * F;        // 256*256 fp16
  unsigned short* w2t = w1t + 65536;                // 256*256 fp16
  int*   esrc   = (int*)(w2t + 65536);              // Ee
  int*   counts = esrc + Ee;                        // Nn
  int*   offs   = counts + Nn;                      // Nn
  int*   cursor = offs + Nn;                        // Nn
  int*   bsum   = cursor + Nn;                      // 256
  int*   bofs   = bsum + 256;                       // 256
  float* el1p   = (float*)(bofs + 256);             // Nn*2
  float* er1p   = el1p + (size_t)Nn * 2;            // Nn*2
  float* el2p   = er1p + (size_t)Nn * 2;            // Nn
  float* er2p   = el2p + Nn;                        // Nn

  dim3 blk(256);

  // ---- input conversions ----
  cvt_half<<<(Nn * 64 + 255) / 256, blk, 0, stream>>>((const float4*)x, (uint2*)xh, Nn * 64);
  transpose_w<<<256, blk, 0, stream>>>(W1, w1t);
  transpose_w<<<256, blk, 0, stream>>>(W2, w2t);

  // ---- CSR build (once, shared by both layers) ----
  zero_f4<<<(Nn / 4 + 255) / 256, blk, 0, stream>>>((float4*)counts, Nn / 4);
  hist_dst<<<(Ee + 255) / 256, blk, 0, stream>>>(dst, counts, Ee);
  scan_block<<<NB, blk, 0, stream>>>(counts, offs, bsum, Nn);
  scan_bsum<<<1, blk, 0, stream>>>(bsum, bofs, NB);
  scan_add<<<NB, blk, 0, stream>>>(offs, bofs, cursor, Nn);
  scatter_edges<<<(Ee + 255) / 256, blk, 0, stream>>>(src, dst, cursor, esrc, Ee);

  const int gg = (Nn + 63) / 64;

  // ---- layer 1 (heads=2, d=128) ----
  gemm_mfma<<<gg, blk, 0, stream>>>(xh, w1t, z, Nn);
  attn_dots<<<(Nn * 2 + 3) / 4, blk, 0, stream>>>(z, al1, ar1, el1p, er1p, Nn * 2, 1, 128);
  node_aggregate<1, 7, 1, 1><<<(Nn + 3) / 4, blk, 0, stream>>>(z, el1p, er1p, esrc, offs,
                                                               counts, b1, xh, Nn);  // h -> xh (fp16)

  // ---- layer 2 (heads=1, d=256) ----
  gemm_mfma<<<gg, blk, 0, stream>>>(xh, w2t, z, Nn);  // z2 = h @ W2
  attn_dots<<<(Nn + 3) / 4, blk, 0, stream>>>(z, al2, ar2, el2p, er2p, Nn, 0, 256);
  node_aggregate<0, 8, 0, 0><<<(Nn + 3) / 4, blk, 0, stream>>>(z, el2p, er2p, esrc, offs,
                                                               counts, b2, out, Nn);
}